// Round 10
// baseline (169.579 us; speedup 1.0000x reference)
//
#include <hip/hip_runtime.h>

#define NN 20
#define NP 125          // 5^3 window
#define NV (NN*NN*NN)   // 8000

__device__ __forceinline__ float rlf(float v, int l) {
    return __uint_as_float(__builtin_amdgcn_readlane(__float_as_uint(v), l));
}

// ---------------------------------------------------------------------------
// prep: blocks 0..124  -> k_rel[p][c]  = bk + relpos_flat[p] @ Wk[0:96]
//                         vrelW[p][c]  = (bv + relpos_flat[p] @ Wv[0:96]) @ Wo
//       blocks 125..188 -> Wvo[d][c]   = Wv[96+d][:] @ Wo     (64x64)
// ---------------------------------------------------------------------------
__global__ __launch_bounds__(64) void prep(
        const float* __restrict__ rpw,
        const float* __restrict__ Wk, const float* __restrict__ bk,
        const float* __restrict__ Wv, const float* __restrict__ bv,
        const float* __restrict__ Wo,
        float* __restrict__ k_rel, float* __restrict__ vrelW,
        float* __restrict__ Wvo) {
    const int c = threadIdx.x;
    if (blockIdx.x < NP) {
        const int p = blockIdx.x;
        const int d3 = p / 25, d4 = (p / 5) % 5, d5 = p % 5;
        __shared__ float vtmp[64];
        float ak = bk[c], av = bv[c];
#pragma unroll
        for (int t = 0; t < 96; ++t) {
            const int blk = t >> 5, off = t & 31;
            const int row = (blk == 0) ? d3 : (blk == 1) ? d4 : d5;
            const float r = rpw[row * 32 + off];
            ak = fmaf(r, Wk[t * 64 + c], ak);
            av = fmaf(r, Wv[t * 64 + c], av);
        }
        k_rel[p * 64 + c] = ak;
        vtmp[c] = av;
        __syncthreads();
        float o = 0.f;
#pragma unroll 8
        for (int e = 0; e < 64; ++e)
            o = fmaf(vtmp[e], Wo[e * 64 + c], o);
        vrelW[p * 64 + c] = o;
    } else {
        const int d = blockIdx.x - NP;
        float acc = 0.f;
#pragma unroll 8
        for (int e = 0; e < 64; ++e)
            acc = fmaf(Wv[(96 + d) * 64 + e], Wo[e * 64 + c], acc);
        Wvo[d * 64 + c] = acc;
    }
}

// ---------------------------------------------------------------------------
// qkv2 (r6-proven lean version): Q = SE@Wq + bq ; Km = SE@Wk[96:] ; VW = SE@Wvo
// 250 blocks x 256 threads, 32 voxels/block (8 per wave).
// ---------------------------------------------------------------------------
__global__ __launch_bounds__(256) void qkv2(
        const float* __restrict__ SE,
        const float* __restrict__ Wq, const float* __restrict__ bq,
        const float* __restrict__ Wk, const float* __restrict__ Wvo,
        float* __restrict__ Q, float* __restrict__ Km, float* __restrict__ VW) {
    __shared__ float se_s[32][65];
    const int t = threadIdx.x;
    const int vbase = blockIdx.x * 32;
    {
        const float4* __restrict__ src = (const float4*)(SE + vbase * 64);
        const float4 a = src[t];
        const float4 b = src[t + 256];
        const int r0 = t >> 4,        c0 = (t & 15) * 4;
        const int r1 = (t + 256) >> 4;
        se_s[r0][c0 + 0] = a.x; se_s[r0][c0 + 1] = a.y;
        se_s[r0][c0 + 2] = a.z; se_s[r0][c0 + 3] = a.w;
        se_s[r1][c0 + 0] = b.x; se_s[r1][c0 + 1] = b.y;
        se_s[r1][c0 + 2] = b.z; se_s[r1][c0 + 3] = b.w;
    }
    __syncthreads();
    const int lane = t & 63, w = t >> 6;
    float aq[8], ak[8], av[8];
#pragma unroll
    for (int j = 0; j < 8; ++j) { aq[j] = bq[lane]; ak[j] = 0.f; av[j] = 0.f; }
#pragma unroll 8
    for (int d = 0; d < 64; ++d) {
        const float wq = Wq[d * 64 + lane];
        const float wk = Wk[(96 + d) * 64 + lane];
        const float wv = Wvo[d * 64 + lane];
#pragma unroll
        for (int j = 0; j < 8; ++j) {
            const float s = se_s[w * 8 + j][d];   // uniform addr -> broadcast
            aq[j] = fmaf(s, wq, aq[j]);
            ak[j] = fmaf(s, wk, ak[j]);
            av[j] = fmaf(s, wv, av[j]);
        }
    }
#pragma unroll
    for (int j = 0; j < 8; ++j) {
        const int v = vbase + w * 8 + j;
        Q[v * 64 + lane]  = aq[j];
        Km[v * 64 + lane] = ak[j];
        VW[v * 64 + lane] = av[j];
    }
}

// ---------------------------------------------------------------------------
// attn8: attn7 structure with the q.k_rel dot computed INLINE pre-barrier
// (global float4 gathers of k_rel, L1/L2-hot, overlapped with Km staging
// latency) instead of the precomputed qkr array (which made qkv heavy).
// Block = 512 thr (8 waves) = 2x2x2 tile; grid 1000, XCD cubic chunking
// (r6-proven: FETCH 183MB->4.8MB). Stride-68 union buffer; readlane
// broadcasts; scores in registers, bpermute-free redistribution.
// REFERENCE QUIRKS: gather coord = (x+e4-2, y+e3-2, z+e5-2) [x/y digit swap];
// mask coord = (x+e3-2, y+e4-2, z+e5-2) in [1,19]^3; masked score exactly 0;
// OOB gather rows zero-filled at staging (= reference zero padding).
// ---------------------------------------------------------------------------
__global__ __launch_bounds__(512, 2) void attn8(
        const float* __restrict__ Q, const float* __restrict__ Km,
        const float* __restrict__ VW,
        const float* __restrict__ k_rel, const float* __restrict__ vrelW,
        const float* __restrict__ bo,
        float* __restrict__ out) {
    __shared__ __align__(16) float u[216 * 68];   // 58.75 KB union buffer

    const int tid  = threadIdx.x;
    const int lane = tid & 63;
    const int w    = tid >> 6;

    // ---- XCD-aware cubic chunking ----
    const int chunk = blockIdx.x & 7;
    const int idx   = blockIdx.x >> 3;
    const int cx = chunk >> 2, cy = (chunk >> 1) & 1, cz = chunk & 1;
    const int TX = cx * 5 + idx / 25;
    const int TY = cy * 5 + (idx / 5) % 5;
    const int TZ = cz * 5 + idx % 5;

    const int wx = w >> 2, wy = (w >> 1) & 1, wz = w & 1;
    const int x = TX * 2 + wx, y = TY * 2 + wy, z = TZ * 2 + wz;
    const int v = (x * NN + y) * NN + z;

    // ---- stage Km union (216 rows, zero-fill OOB) ----
    for (int i = tid; i < 216 * 16; i += 512) {
        const int row = i >> 4, ch = i & 15;
        const int ux = row / 36, uy = (row / 6) % 6, uz = row % 6;
        const int gX = TX * 2 - 2 + ux;
        const int gY = TY * 2 - 2 + uy;
        const int gZ = TZ * 2 - 2 + uz;
        float4 val = make_float4(0.f, 0.f, 0.f, 0.f);
        if ((unsigned)gX <= 19u && (unsigned)gY <= 19u && (unsigned)gZ <= 19u)
            val = ((const float4*)Km)[((gX * NN + gY) * NN + gZ) * 16 + ch];
        *(float4*)&u[row * 68 + ch * 4] = val;
    }

    const float q = Q[v * 64 + lane];

    // ---- per-lane union rows r_m = lane + 64m: geometry + validity ----
    int  rr0, rr1, rr2, rr3;
    int  pc0, pc1, pc2, pc3;
    bool vd0, vd1, vd2, vd3;
#define GEO(M, RR, PC, VD)                                                     \
    {                                                                          \
        const int r = lane + 64 * (M);                                         \
        const bool okr = (r < 216);                                            \
        const int rc = okr ? r : 0;                                            \
        const int ux = rc / 36, uy = (rc / 6) % 6, uz = rc % 6;                \
        const int E4 = ux - wx, E3 = uy - wy, E5 = uz - wz;                    \
        const bool win = okr && (unsigned)E3 <= 4u && (unsigned)E4 <= 4u &&    \
                         (unsigned)E5 <= 4u;                                   \
        const bool mv = win && (unsigned)(x + E3 - 3) <= 18u &&                \
                        (unsigned)(y + E4 - 3) <= 18u &&                       \
                        (unsigned)(z + E5 - 3) <= 18u;                         \
        RR = rc; VD = mv;                                                      \
        PC = mv ? (25 * E3 + 5 * E4 + E5) : 0;                                 \
    }
    GEO(0, rr0, pc0, vd0)
    GEO(1, rr1, pc1, vd1)
    GEO(2, rr2, pc2, vd2)
    GEO(3, rr3, pc3, vd3)
#undef GEO

    // ---- qk_rel dots (global k_rel, L1/L2-hot) — overlaps staging wait ----
    float qk0 = 0.f, qk1 = 0.f, qk2 = 0.f, qk3 = 0.f;
    const float4* __restrict__ KR = (const float4*)k_rel;
#pragma unroll
    for (int i = 0; i < 16; ++i) {
        const float qa = rlf(q, 4 * i + 0);
        const float qb = rlf(q, 4 * i + 1);
        const float qc = rlf(q, 4 * i + 2);
        const float qd = rlf(q, 4 * i + 3);
        const float4 k0 = KR[pc0 * 16 + i];
        const float4 k1 = KR[pc1 * 16 + i];
        const float4 k2 = KR[pc2 * 16 + i];
        const float4 k3 = KR[pc3 * 16 + i];
        qk0 = fmaf(k0.x, qa, qk0); qk0 = fmaf(k0.y, qb, qk0);
        qk0 = fmaf(k0.z, qc, qk0); qk0 = fmaf(k0.w, qd, qk0);
        qk1 = fmaf(k1.x, qa, qk1); qk1 = fmaf(k1.y, qb, qk1);
        qk1 = fmaf(k1.z, qc, qk1); qk1 = fmaf(k1.w, qd, qk1);
        qk2 = fmaf(k2.x, qa, qk2); qk2 = fmaf(k2.y, qb, qk2);
        qk2 = fmaf(k2.z, qc, qk2); qk2 = fmaf(k2.w, qd, qk2);
        qk3 = fmaf(k3.x, qa, qk3); qk3 = fmaf(k3.y, qb, qk3);
        qk3 = fmaf(k3.z, qc, qk3); qk3 = fmaf(k3.w, qd, qk3);
    }

    __syncthreads();   // Km union staged

    // ---- logits: b128 LDS reads + readlane q ----
    float a0 = 0.f, a1 = 0.f, a2 = 0.f, a3 = 0.f;
#pragma unroll
    for (int i = 0; i < 16; ++i) {
        const float qa = rlf(q, 4 * i + 0);
        const float qb = rlf(q, 4 * i + 1);
        const float qc = rlf(q, 4 * i + 2);
        const float qd = rlf(q, 4 * i + 3);
        const float4 k0 = *(const float4*)&u[rr0 * 68 + 4 * i];
        const float4 k1 = *(const float4*)&u[rr1 * 68 + 4 * i];
        const float4 k2 = *(const float4*)&u[rr2 * 68 + 4 * i];
        const float4 k3 = *(const float4*)&u[rr3 * 68 + 4 * i];
        a0 = fmaf(k0.x, qa, a0); a0 = fmaf(k0.y, qb, a0);
        a0 = fmaf(k0.z, qc, a0); a0 = fmaf(k0.w, qd, a0);
        a1 = fmaf(k1.x, qa, a1); a1 = fmaf(k1.y, qb, a1);
        a1 = fmaf(k1.z, qc, a1); a1 = fmaf(k1.w, qd, a1);
        a2 = fmaf(k2.x, qa, a2); a2 = fmaf(k2.y, qb, a2);
        a2 = fmaf(k2.z, qc, a2); a2 = fmaf(k2.w, qd, a2);
        a3 = fmaf(k3.x, qa, a3); a3 = fmaf(k3.y, qb, a3);
        a3 = fmaf(k3.z, qc, a3); a3 = fmaf(k3.w, qd, a3);
    }
    const float l0 = vd0 ? a0 + qk0 : -1e9f;
    const float l1 = vd1 ? a1 + qk1 : -1e9f;
    const float l2 = vd2 ? a2 + qk2 : -1e9f;
    const float l3 = vd3 ? a3 + qk3 : -1e9f;

    // ---- softmax over union slots (invalid -> exp 0) ----
    float mm = fmaxf(fmaxf(l0, l1), fmaxf(l2, l3));
#pragma unroll
    for (int d = 1; d < 64; d <<= 1) mm = fmaxf(mm, __shfl_xor(mm, d));
    const float e0 = __expf(l0 - mm);
    const float e1 = __expf(l1 - mm);
    const float e2 = __expf(l2 - mm);
    const float e3v = __expf(l3 - mm);
    float ss = ((e0 + e1) + (e2 + e3v));
#pragma unroll
    for (int d = 1; d < 64; d <<= 1) ss += __shfl_xor(ss, d);
    const float inv = 1.f / ss;
    const float sA = e0 * inv, sB = e1 * inv, sC = e2 * inv, sD = e3v * inv;

    // ---- redistribute: score of p -> lane p (s0: p=lane, s1: p=64+lane) ----
    int d3 = lane / 25, d4 = (lane / 5) % 5, d5 = lane % 5;
    const int r0 = 36 * (wx + d4) + 6 * (wy + d3) + (wz + d5);
    const int p1c = (lane + 64 < NP) ? (lane + 64) : (NP - 1);
    d3 = p1c / 25; d4 = (p1c / 5) % 5; d5 = p1c % 5;
    const int r1 = 36 * (wx + d4) + 6 * (wy + d3) + (wz + d5);
    const float cA0 = __shfl(sA, r0 & 63), cB0 = __shfl(sB, r0 & 63);
    const float cC0 = __shfl(sC, r0 & 63), cD0 = __shfl(sD, r0 & 63);
    const int sl0 = r0 >> 6;
    const float s0 = (sl0 == 0) ? cA0 : (sl0 == 1) ? cB0 : (sl0 == 2) ? cC0 : cD0;
    const float cA1 = __shfl(sA, r1 & 63), cB1 = __shfl(sB, r1 & 63);
    const float cC1 = __shfl(sC, r1 & 63), cD1 = __shfl(sD, r1 & 63);
    const int sl1 = r1 >> 6;
    const float s1 = (sl1 == 0) ? cA1 : (sl1 == 1) ? cB1 : (sl1 == 2) ? cC1 : cD1;

    __syncthreads();   // all u(Km) reads done -> u reusable

    // ---- stage VW union (reuses u) ----
    for (int i = tid; i < 216 * 16; i += 512) {
        const int row = i >> 4, ch = i & 15;
        const int ux = row / 36, uy = (row / 6) % 6, uz = row % 6;
        const int gX = TX * 2 - 2 + ux;
        const int gY = TY * 2 - 2 + uy;
        const int gZ = TZ * 2 - 2 + uz;
        float4 val = make_float4(0.f, 0.f, 0.f, 0.f);
        if ((unsigned)gX <= 19u && (unsigned)gY <= 19u && (unsigned)gZ <= 19u)
            val = ((const float4*)VW)[((gX * NN + gY) * NN + gZ) * 16 + ch];
        *(float4*)&u[row * 68 + ch * 4] = val;
    }
    __syncthreads();

    // ---- weighted sum: lane = channel; scores via literal readlane ----
    float A0 = 0.f, A1 = 0.f, A2 = 0.f, A3 = 0.f, A4 = 0.f;
    const float* __restrict__ vr = vrelW + lane;
#pragma unroll 5
    for (int g = 0; g < 25; ++g) {
        const int ge3 = g / 5, ge4 = g % 5;
        const int rb = 36 * (wx + ge4) + 6 * (wy + ge3) + wz;
        const int pb = g * 5;
#define STEP(J, ACC)                                                           \
        {                                                                      \
            const int p = pb + (J);                                            \
            const float sc = (p < 64) ? rlf(s0, p) : rlf(s1, p - 64);          \
            ACC = fmaf(sc, u[(rb + (J)) * 68 + lane] + vr[p * 64], ACC);       \
        }
        STEP(0, A0) STEP(1, A1) STEP(2, A2) STEP(3, A3) STEP(4, A4)
#undef STEP
    }
    const float rw = ((A0 + A1) + (A2 + A3)) + A4;
    out[v * 64 + lane] = rw + bo[lane];
}

// ---------------------------------------------------------------------------
extern "C" void kernel_launch(void* const* d_in, const int* in_sizes, int n_in,
                              void* d_out, int out_size, void* d_ws, size_t ws_size,
                              hipStream_t stream) {
    const float* SE  = (const float*)d_in[0];
    const float* rpw = (const float*)d_in[1];
    const float* Wq  = (const float*)d_in[2];
    const float* bq  = (const float*)d_in[3];
    const float* Wk  = (const float*)d_in[4];
    const float* bk  = (const float*)d_in[5];
    const float* Wv  = (const float*)d_in[6];
    const float* bv  = (const float*)d_in[7];
    const float* Wo  = (const float*)d_in[8];
    const float* bo  = (const float*)d_in[9];
    float* out = (float*)d_out;

    float* ws    = (float*)d_ws;
    float* Q     = ws;                 // 8000*64
    float* Km    = ws + 512000;        // 8000*64
    float* VW    = ws + 1024000;       // 8000*64
    float* k_rel = ws + 1536000;       // 125*64
    float* vrelW = ws + 1544000;       // 125*64
    float* Wvo   = ws + 1552000;       // 64*64

    prep<<<NP + 64, 64, 0, stream>>>(rpw, Wk, bk, Wv, bv, Wo, k_rel, vrelW, Wvo);
    qkv2<<<NV / 32, 256, 0, stream>>>(SE, Wq, bq, Wk, Wvo, Q, Km, VW);
    attn8<<<1000, 512, 0, stream>>>(Q, Km, VW, k_rel, vrelW, bo, out);
}

// Round 11
// 144.795 us; speedup vs baseline: 1.1712x; 1.1712x over previous
//
#include <hip/hip_runtime.h>

#define NN 20
#define NP 125          // 5^3 window
#define NV (NN*NN*NN)   // 8000

__device__ __forceinline__ float rlf(float v, int l) {
    return __uint_as_float(__builtin_amdgcn_readlane(__float_as_uint(v), l));
}

// ---------------------------------------------------------------------------
// prep: blocks 0..124  -> k_rel[p][c]  = bk + relpos_flat[p] @ Wk[0:96]
//                         vrelW[p][c]  = (bv + relpos_flat[p] @ Wv[0:96]) @ Wo
//       blocks 125..188 -> Wvo[d][c]   = Wv[96+d][:] @ Wo     (64x64)
// ---------------------------------------------------------------------------
__global__ __launch_bounds__(64) void prep(
        const float* __restrict__ rpw,
        const float* __restrict__ Wk, const float* __restrict__ bk,
        const float* __restrict__ Wv, const float* __restrict__ bv,
        const float* __restrict__ Wo,
        float* __restrict__ k_rel, float* __restrict__ vrelW,
        float* __restrict__ Wvo) {
    const int c = threadIdx.x;
    if (blockIdx.x < NP) {
        const int p = blockIdx.x;
        const int d3 = p / 25, d4 = (p / 5) % 5, d5 = p % 5;
        __shared__ float vtmp[64];
        float ak = bk[c], av = bv[c];
#pragma unroll
        for (int t = 0; t < 96; ++t) {
            const int blk = t >> 5, off = t & 31;
            const int row = (blk == 0) ? d3 : (blk == 1) ? d4 : d5;
            const float r = rpw[row * 32 + off];
            ak = fmaf(r, Wk[t * 64 + c], ak);
            av = fmaf(r, Wv[t * 64 + c], av);
        }
        k_rel[p * 64 + c] = ak;
        vtmp[c] = av;
        __syncthreads();
        float o = 0.f;
#pragma unroll 8
        for (int e = 0; e < 64; ++e)
            o = fmaf(vtmp[e], Wo[e * 64 + c], o);
        vrelW[p * 64 + c] = o;
    } else {
        const int d = blockIdx.x - NP;
        float acc = 0.f;
#pragma unroll 8
        for (int e = 0; e < 64; ++e)
            acc = fmaf(Wv[(96 + d) * 64 + e], Wo[e * 64 + c], acc);
        Wvo[d * 64 + c] = acc;
    }
}

// ---------------------------------------------------------------------------
// qkv4: qkv2 + fused qkr[v][p] = Q[v].k_rel[p].
// k_rel staged in LDS at stride 68 with XOR swizzle XK(p)=((p>>3)&7)<<2 ->
// aligned ds_read_b128, <=2-way banks (2-way free). q broadcast via readlane.
// 250 blocks x 256 threads, 32 voxels/block (8 per wave).
// ---------------------------------------------------------------------------
__global__ __launch_bounds__(256) void qkv4(
        const float* __restrict__ SE,
        const float* __restrict__ Wq, const float* __restrict__ bq,
        const float* __restrict__ Wk, const float* __restrict__ Wvo,
        const float* __restrict__ k_rel,
        float* __restrict__ Q, float* __restrict__ Km, float* __restrict__ VW,
        float* __restrict__ qkr) {
    __shared__ float se_s[32][65];
    __shared__ __align__(16) float krs[125 * 68];
    const int t = threadIdx.x;
    const int vbase = blockIdx.x * 32;
    {   // stage 32x64 SE floats
        const float4* __restrict__ src = (const float4*)(SE + vbase * 64);
        const float4 a = src[t];
        const float4 b = src[t + 256];
        const int r0 = t >> 4,        c0 = (t & 15) * 4;
        const int r1 = (t + 256) >> 4;
        se_s[r0][c0 + 0] = a.x; se_s[r0][c0 + 1] = a.y;
        se_s[r0][c0 + 2] = a.z; se_s[r0][c0 + 3] = a.w;
        se_s[r1][c0 + 0] = b.x; se_s[r1][c0 + 1] = b.y;
        se_s[r1][c0 + 2] = b.z; se_s[r1][c0 + 3] = b.w;
    }
    // stage k_rel swizzled: krs[p*68 + (c4 ^ XK(p))]
    for (int i = t; i < 125 * 16; i += 256) {
        const int row = i >> 4, ch4 = (i & 15) * 4;
        const float4 val = ((const float4*)k_rel)[row * 16 + (ch4 >> 2)];
        const int xk = ((row >> 3) & 7) << 2;
        *(float4*)&krs[row * 68 + (ch4 ^ xk)] = val;
    }
    __syncthreads();
    const int lane = t & 63, w = t >> 6;
    float aq[8], ak[8], av[8];
#pragma unroll
    for (int j = 0; j < 8; ++j) { aq[j] = bq[lane]; ak[j] = 0.f; av[j] = 0.f; }
#pragma unroll 8
    for (int d = 0; d < 64; ++d) {
        const float wq = Wq[d * 64 + lane];
        const float wk = Wk[(96 + d) * 64 + lane];
        const float wv = Wvo[d * 64 + lane];
#pragma unroll
        for (int j = 0; j < 8; ++j) {
            const float s = se_s[w * 8 + j][d];   // uniform addr -> broadcast
            aq[j] = fmaf(s, wq, aq[j]);
            ak[j] = fmaf(s, wk, ak[j]);
            av[j] = fmaf(s, wv, av[j]);
        }
    }
#pragma unroll
    for (int j = 0; j < 8; ++j) {
        const int v = vbase + w * 8 + j;
        Q[v * 64 + lane]  = aq[j];
        Km[v * 64 + lane] = ak[j];
        VW[v * 64 + lane] = av[j];
    }
    // fused qkr: lane = p (2 p's), aligned swizzled b128 krs reads
    const int p0 = lane;
    const int p1c = (lane + 64 < NP) ? (lane + 64) : (NP - 1);
    const int xk0 = ((p0 >> 3) & 7) << 2;
    const int xk1 = ((p1c >> 3) & 7) << 2;
#pragma unroll
    for (int j = 0; j < 8; ++j) {
        float d0 = 0.f, d1 = 0.f;
#pragma unroll
        for (int i = 0; i < 16; ++i) {
            const float qa = rlf(aq[j], 4 * i + 0);
            const float qb = rlf(aq[j], 4 * i + 1);
            const float qc = rlf(aq[j], 4 * i + 2);
            const float qd = rlf(aq[j], 4 * i + 3);
            const float4 k0 = *(const float4*)&krs[p0 * 68 + ((4 * i) ^ xk0)];
            const float4 k1 = *(const float4*)&krs[p1c * 68 + ((4 * i) ^ xk1)];
            d0 = fmaf(k0.x, qa, d0); d0 = fmaf(k0.y, qb, d0);
            d0 = fmaf(k0.z, qc, d0); d0 = fmaf(k0.w, qd, d0);
            d1 = fmaf(k1.x, qa, d1); d1 = fmaf(k1.y, qb, d1);
            d1 = fmaf(k1.z, qc, d1); d1 = fmaf(k1.w, qd, d1);
        }
        const int v = vbase + w * 8 + j;
        qkr[v * 128 + lane] = d0;
        qkr[v * 128 + 64 + lane] = d1;   // slots >=125 masked downstream
    }
}

// ---------------------------------------------------------------------------
// attn9: r6 attn4 skeleton (2 p/lane, sc_s scores, 3 barriers, XCD cubic
// chunking: FETCH 183MB->4.8MB proven) with three surgical fixes:
//  - u at stride 68 + XOR swizzle XU(row)=(((row>>3)^(row>>6))&7)<<2 ->
//    logits are aligned ds_read_b128, <=2-way banks (free); wsum reads stay
//    conflict-free (lane XOR is a bijection).
//  - q.k_rel via precomputed qkr (2 coalesced scalar loads) -- removes the
//    divergent k_rel gathers that dominated attn4 (r10 lesson).
//  - T14 async-stage: VW global loads issued after barrier 1 (in flight
//    across logits+softmax), ds_written after barrier 2.
// REFERENCE QUIRKS: gather coord = (x+e4-2, y+e3-2, z+e5-2) [x/y digit swap];
// mask coord = (x+e3-2, y+e4-2, z+e5-2) in [1,19]^3; masked score exactly 0;
// OOB gather rows zero-filled at staging (= reference zero padding).
// ---------------------------------------------------------------------------
#define XU(row) ((((row >> 3) ^ (row >> 6)) & 7) << 2)

__global__ __launch_bounds__(512, 4) void attn9(
        const float* __restrict__ Q, const float* __restrict__ Km,
        const float* __restrict__ VW, const float* __restrict__ qkr,
        const float* __restrict__ vrelW, const float* __restrict__ bo,
        float* __restrict__ out) {
    __shared__ __align__(16) float u[216 * 68];   // 57.4 KB
    __shared__ float sc_s[8][128];

    const int tid  = threadIdx.x;
    const int lane = tid & 63;
    const int w    = tid >> 6;

    // ---- XCD-aware cubic chunking ----
    const int chunk = blockIdx.x & 7;
    const int idx   = blockIdx.x >> 3;
    const int cx = chunk >> 2, cy = (chunk >> 1) & 1, cz = chunk & 1;
    const int TX = cx * 5 + idx / 25;
    const int TY = cy * 5 + (idx / 5) % 5;
    const int TZ = cz * 5 + idx % 5;

    const int wx = w >> 2, wy = (w >> 1) & 1, wz = w & 1;
    const int x = TX * 2 + wx, y = TY * 2 + wy, z = TZ * 2 + wz;
    const int v = (x * NN + y) * NN + z;

    // ---- stage Km union (216 rows, zero-fill OOB, swizzled) ----
    for (int i = tid; i < 216 * 16; i += 512) {
        const int row = i >> 4, ch4 = (i & 15) * 4;
        const int ux = row / 36, uy = (row / 6) % 6, uz = row % 6;
        const int gX = TX * 2 - 2 + ux;
        const int gY = TY * 2 - 2 + uy;
        const int gZ = TZ * 2 - 2 + uz;
        float4 val = make_float4(0.f, 0.f, 0.f, 0.f);
        if ((unsigned)gX <= 19u && (unsigned)gY <= 19u && (unsigned)gZ <= 19u)
            val = ((const float4*)Km)[((gX * NN + gY) * NN + gZ) * 16 + (ch4 >> 2)];
        *(float4*)&u[row * 68 + (ch4 ^ XU(row))] = val;
    }

    const float q = Q[v * 64 + lane];
    const float qk0 = qkr[v * 128 + lane];          // coalesced
    const float qk1 = qkr[v * 128 + 64 + lane];     // coalesced

    // ---- geometry for p0 = lane, p1 = lane + 64 (digit-swap quirk) ----
    const int p0 = lane;
    const int p1 = lane + 64;
    const int p1c = (p1 < NP) ? p1 : (NP - 1);

    int e3 = p0 / 25, e4 = (p0 / 5) % 5, e5 = p0 % 5;
    const int row0 = 36 * (wx + e4) + 6 * (wy + e3) + (wz + e5);
    const bool mv0 = ((unsigned)(x + e3 - 3) <= 18u) &&
                     ((unsigned)(y + e4 - 3) <= 18u) &&
                     ((unsigned)(z + e5 - 3) <= 18u);
    e3 = p1c / 25; e4 = (p1c / 5) % 5; e5 = p1c % 5;
    const int row1 = 36 * (wx + e4) + 6 * (wy + e3) + (wz + e5);
    const bool mv1 = (p1 < NP) &&
                     ((unsigned)(x + e3 - 3) <= 18u) &&
                     ((unsigned)(y + e4 - 3) <= 18u) &&
                     ((unsigned)(z + e5 - 3) <= 18u);
    const int xu0 = XU(row0), xu1 = XU(row1);

    __syncthreads();   // barrier 1: Km union staged

    // ---- T14: issue VW prefetch loads (drain at barrier 2, hidden) ----
    float4 vwreg[7];
#pragma unroll
    for (int k = 0; k < 7; ++k) {
        const int i = tid + 512 * k;
        float4 val = make_float4(0.f, 0.f, 0.f, 0.f);
        if (i < 216 * 16) {
            const int row = i >> 4, ch = i & 15;
            const int ux = row / 36, uy = (row / 6) % 6, uz = row % 6;
            const int gX = TX * 2 - 2 + ux;
            const int gY = TY * 2 - 2 + uy;
            const int gZ = TZ * 2 - 2 + uz;
            if ((unsigned)gX <= 19u && (unsigned)gY <= 19u && (unsigned)gZ <= 19u)
                val = ((const float4*)VW)[((gX * NN + gY) * NN + gZ) * 16 + ch];
        }
        vwreg[k] = val;
    }

    // ---- logits: aligned swizzled b128 LDS reads ----
    float a0 = 0.f, a1 = 0.f;
#pragma unroll
    for (int i = 0; i < 16; ++i) {
        const float qa = rlf(q, 4 * i + 0);
        const float qb = rlf(q, 4 * i + 1);
        const float qc = rlf(q, 4 * i + 2);
        const float qd = rlf(q, 4 * i + 3);
        const float4 k0 = *(const float4*)&u[row0 * 68 + ((4 * i) ^ xu0)];
        const float4 k1 = *(const float4*)&u[row1 * 68 + ((4 * i) ^ xu1)];
        a0 = fmaf(k0.x, qa, a0); a0 = fmaf(k0.y, qb, a0);
        a0 = fmaf(k0.z, qc, a0); a0 = fmaf(k0.w, qd, a0);
        a1 = fmaf(k1.x, qa, a1); a1 = fmaf(k1.y, qb, a1);
        a1 = fmaf(k1.z, qc, a1); a1 = fmaf(k1.w, qd, a1);
    }
    const float l0 = mv0 ? a0 + qk0 : -1e9f;
    const float l1 = mv1 ? a1 + qk1 : -1e9f;

    // ---- softmax over 125 ----
    float m = fmaxf(l0, l1);
#pragma unroll
    for (int d = 1; d < 64; d <<= 1) m = fmaxf(m, __shfl_xor(m, d));
    const float e0 = __expf(l0 - m);
    const float e1 = __expf(l1 - m);
    float ssum = e0 + e1;
#pragma unroll
    for (int d = 1; d < 64; d <<= 1) ssum += __shfl_xor(ssum, d);
    const float inv = 1.f / ssum;
    sc_s[w][p0] = e0 * inv;
    sc_s[w][p1] = e1 * inv;   // p1 up to 127; clamped lanes store exact 0
    __syncthreads();   // barrier 2: u(Km) reads done + VW loads drained

    // ---- write prefetched VW union (swizzled) ----
#pragma unroll
    for (int k = 0; k < 7; ++k) {
        const int i = tid + 512 * k;
        if (i < 216 * 16) {
            const int row = i >> 4, ch4 = (i & 15) * 4;
            *(float4*)&u[row * 68 + (ch4 ^ XU(row))] = vwreg[k];
        }
    }
    __syncthreads();   // barrier 3: VW union staged

    // ---- weighted sum: lane = channel; swizzled scalar reads (bijective) ---
    float A0 = 0.f, A1 = 0.f, A2 = 0.f, A3 = 0.f, A4 = 0.f;
    const float* __restrict__ vr = vrelW + lane;
#pragma unroll 5
    for (int g = 0; g < 25; ++g) {
        const int ge3 = g / 5, ge4 = g % 5;
        const int rb = 36 * (wx + ge4) + 6 * (wy + ge3) + wz;
        const int pb = g * 5;
#define STEP(J, ACC)                                                           \
        {                                                                      \
            const int rr = rb + (J);                                           \
            const float sc = sc_s[w][pb + (J)];                                \
            ACC = fmaf(sc, u[rr * 68 + (lane ^ XU(rr))] + vr[(pb + (J)) * 64], \
                       ACC);                                                   \
        }
        STEP(0, A0) STEP(1, A1) STEP(2, A2) STEP(3, A3) STEP(4, A4)
#undef STEP
    }
    const float rw = ((A0 + A1) + (A2 + A3)) + A4;
    out[v * 64 + lane] = rw + bo[lane];
}

// ---------------------------------------------------------------------------
extern "C" void kernel_launch(void* const* d_in, const int* in_sizes, int n_in,
                              void* d_out, int out_size, void* d_ws, size_t ws_size,
                              hipStream_t stream) {
    const float* SE  = (const float*)d_in[0];
    const float* rpw = (const float*)d_in[1];
    const float* Wq  = (const float*)d_in[2];
    const float* bq  = (const float*)d_in[3];
    const float* Wk  = (const float*)d_in[4];
    const float* bk  = (const float*)d_in[5];
    const float* Wv  = (const float*)d_in[6];
    const float* bv  = (const float*)d_in[7];
    const float* Wo  = (const float*)d_in[8];
    const float* bo  = (const float*)d_in[9];
    float* out = (float*)d_out;

    float* ws    = (float*)d_ws;
    float* Q     = ws;                 // 8000*64
    float* Km    = ws + 512000;        // 8000*64
    float* VW    = ws + 1024000;       // 8000*64
    float* k_rel = ws + 1536000;       // 125*64
    float* vrelW = ws + 1544000;       // 125*64
    float* Wvo   = ws + 1552000;       // 64*64
    float* qkr   = ws + 1556096;       // 8000*128

    prep<<<NP + 64, 64, 0, stream>>>(rpw, Wk, bk, Wv, bv, Wo, k_rel, vrelW, Wvo);
    qkv4<<<NV / 32, 256, 0, stream>>>(SE, Wq, bq, Wk, Wvo, k_rel, Q, Km, VW, qkr);
    attn9<<<1000, 512, 0, stream>>>(Q, Km, VW, qkr, vrelW, bo, out);
}